// Round 5
// baseline (414.554 us; speedup 1.0000x reference)
//
#include <hip/hip_runtime.h>

// ---------------- helpers ----------------
typedef __attribute__((ext_vector_type(8))) short bf16x8;   // 8 bf16 = 4 VGPRs
typedef __attribute__((ext_vector_type(4))) float f32x4;

__device__ __forceinline__ float bf2f(unsigned short b) {
    unsigned u = ((unsigned)b) << 16; float f;
    __builtin_memcpy(&f, &u, 4); return f;
}
__device__ __forceinline__ unsigned short f2bf(float f) {
    unsigned u; __builtin_memcpy(&u, &f, 4);
    unsigned r = u + 0x7FFFu + ((u >> 16) & 1u);   // RNE
    return (unsigned short)(r >> 16);
}
__device__ __forceinline__ unsigned packbf(float a, float b) {
    return (unsigned)f2bf(a) | ((unsigned)f2bf(b) << 16);
}
__device__ __forceinline__ float elu1(float v) { return v > 0.f ? v + 1.f : __expf(v); }

__device__ __forceinline__ void async_copy16(const unsigned short* g, unsigned short* l) {
    __builtin_amdgcn_global_load_lds(
        (const __attribute__((address_space(1))) unsigned int*)g,
        (__attribute__((address_space(3))) unsigned int*)l, 16, 0, 0);
}

// tile-col -> channel permutation: lane low holds channels (2*low, 2*low+1) in adjacent ni
__device__ __host__ __forceinline__ int chan_of(int tc) {
    return (tc & ~63) | ((tc & 15) << 1) | ((tc >> 4) & 1) | (((tc >> 5) & 1) << 5);
}
__device__ __forceinline__ int chan_even(int gnb, int p, int low) {
    const int tc = gnb + 32 * p + low;   // ni = 2p  (bit4 = 0)
    return (tc & ~63) | ((tc & 15) << 1) | (((tc >> 5) & 1) << 5);
}

#define EPI_RELU 0     // W1: relu, permuted pair store, natural hbuf
#define EPI_Q 1        // Wq: rotary + Z (needs Ksum), permuted
#define EPI_KV 2       // Wk|Wv interleaved: rotary + KF/VF frag store + Ksum atomics
#define EPI_LN1 3      // Wm: LN1 -> A2 cols 256-511, permuted
#define EPI_LN2RES 4   // W2: LN2 + residual -> d_out fp32, permuted

// ---------------- bf16 GEMM: C[M,N] = A[M,K](lda) @ B^T[N,K] ----------------
// MT=64; NT=128 (non-LN) or 256 (LN, block owns full rows). 256 thr = 4 waves 2x2.
// K-loop: DEEP ring + counted vmcnt. NT=128: PF=4 stages in flight (lead ~4
// iterations of latency cover), ring depth 5, steady wait vmcnt(9).
// NT=256 (LN): PF=2/depth-3 (LDS-capped) — round-4 behavior, in-binary control.
template <int MT, int NT, int EPI>
__global__ __launch_bounds__(256) void gemm_bt(
    const unsigned short* __restrict__ A, int lda,
    const unsigned short* __restrict__ B, int K,
    unsigned short* __restrict__ Cb, int ldc,
    const float* __restrict__ pe,
    const float* __restrict__ KsumC, float* __restrict__ KsumA,
    float* __restrict__ Zbuf, unsigned short* __restrict__ Qpos,
    unsigned short* __restrict__ KF, unsigned short* __restrict__ VF,
    const float* __restrict__ g, const float* __restrict__ bta,
    unsigned short* __restrict__ A2out,
    const float* __restrict__ xres, float* __restrict__ outF)
{
    constexpr int WM = MT / 2, WN = NT / 2, MI = WM / 16, NI = WN / 16;
    constexpr int LPS = 1 + NT / 64;          // loads per stage per thread (vmcnt units)
    constexpr int PF = (NT == 128) ? 4 : 2;   // stages in flight
    constexpr int RD = PF + 1;                // ring depth
    static_assert(MT == 64, "A staging assumes MT*4 == 256 chunks");
    __shared__ unsigned short Asm[RD][MT * 32];
    __shared__ unsigned short Bsm[RD][NT * 32];
    const int t = threadIdx.x;
    const int lane = t & 63, w = t >> 6;
    const int wm = w & 1, wn = w >> 1;
    const int quad = lane >> 4, low = lane & 15;
    const int m0 = blockIdx.x * MT, n0 = blockIdx.y * NT;

    f32x4 acc[MI][NI];
#pragma unroll
    for (int i = 0; i < MI; i++)
#pragma unroll
        for (int j = 0; j < NI; j++) acc[i][j] = (f32x4){0.f, 0.f, 0.f, 0.f};

    // stage one 32-K tile into ring buffer `buf`.
    // source part index is XOR-swizzled so the linear global_load_lds write
    // produces a swizzled LDS layout (swizzle source + read, dest linear).
    auto stage = [&](int k0, int buf) {
        {   // A: 256 chunks, 1 per thread
            const int row = t >> 2;
            const int part = (t & 3) ^ ((t >> 3) & 3);
            async_copy16(A + (size_t)(m0 + row) * lda + k0 + part * 8,
                         &Asm[buf][(w * 64) * 8]);
        }
#pragma unroll
        for (int i = 0; i < NT / 64; i++) {
            const int chunk = i * 256 + t;
            const int row = chunk >> 2;
            const int part = (chunk & 3) ^ ((chunk >> 3) & 3);
            async_copy16(B + (size_t)(n0 + row) * K + k0 + part * 8,
                         &Bsm[buf][(i * 256 + w * 64) * 8]);
        }
    };

    const int nk = K >> 5;                   // >= 8 always
    const int swz = (low >> 1) & 3;          // read-side swizzle key (= (row>>1)&3)
#pragma unroll
    for (int i = 0; i < PF; i++) stage(i << 5, i);
    int kb = 0, sb = PF;                     // read buffer, stage buffer
    for (int ks = 0; ks < nk; ks++) {
        const int rem = nk - 1 - ks;         // stages allowed to stay in flight
        __builtin_amdgcn_sched_barrier(0);
        if constexpr (PF == 4) {             // LPS == 3
            if (rem >= 3)      asm volatile("s_waitcnt vmcnt(9)" ::: "memory");
            else if (rem == 2) asm volatile("s_waitcnt vmcnt(6)" ::: "memory");
            else if (rem == 1) asm volatile("s_waitcnt vmcnt(3)" ::: "memory");
            else               asm volatile("s_waitcnt vmcnt(0)" ::: "memory");
        } else {                             // PF == 2, LPS == 5
            if (rem >= 1)      asm volatile("s_waitcnt vmcnt(5)" ::: "memory");
            else               asm volatile("s_waitcnt vmcnt(0)" ::: "memory");
        }
        __builtin_amdgcn_s_barrier();        // all waves' tile-ks loads landed
        __builtin_amdgcn_sched_barrier(0);
        if (ks + PF < nk) stage((ks + PF) << 5, sb);   // refill freed buffer
        bf16x8 a[MI], b[NI];
#pragma unroll
        for (int mi = 0; mi < MI; mi++)
            a[mi] = *(const bf16x8*)&Asm[kb][(wm * WM + mi * 16 + low) * 32 + ((quad ^ swz)) * 8];
#pragma unroll
        for (int ni = 0; ni < NI; ni++)
            b[ni] = *(const bf16x8*)&Bsm[kb][(wn * WN + ni * 16 + low) * 32 + ((quad ^ swz)) * 8];
#pragma unroll
        for (int mi = 0; mi < MI; mi++)
#pragma unroll
            for (int ni = 0; ni < NI; ni++)
                acc[mi][ni] = __builtin_amdgcn_mfma_f32_16x16x32_bf16(a[mi], b[ni], acc[mi][ni], 0, 0, 0);
        kb = (kb + 1 == RD) ? 0 : kb + 1;
        sb = (sb + 1 == RD) ? 0 : sb + 1;
    }

    const int gmb = m0 + wm * WM, gnb = n0 + wn * WN;

    if constexpr (EPI == EPI_RELU) {
        // permuted pair store, output natural layout [row][ldc]
#pragma unroll
        for (int mi = 0; mi < MI; mi++)
#pragma unroll
            for (int p = 0; p < NI / 2; p++) {
                const int c_e = chan_even(gnb, p, low);
#pragma unroll
                for (int r = 0; r < 4; r++) {
                    const int row = gmb + mi * 16 + quad * 4 + r;
                    const float ve = acc[mi][2 * p][r], vo = acc[mi][2 * p + 1][r];
                    *(unsigned*)&Cb[(size_t)row * ldc + c_e] =
                        packbf(ve > 0.f ? ve : 0.f, vo > 0.f ? vo : 0.f);
                }
            }
    } else if constexpr (EPI == EPI_Q) {
        const int n = m0 >> 12;
#pragma unroll
        for (int p = 0; p < NI / 2; p++) {
            const int c_e = chan_even(gnb, p, low);
            const int head = c_e >> 5;
            const float2 ks = *(const float2*)&KsumC[n * 256 + c_e];
#pragma unroll
            for (int mi = 0; mi < MI; mi++) {
#pragma unroll
                for (int r = 0; r < 4; r++) {
                    const int row = gmb + mi * 16 + quad * 4 + r;
                    const float4 cs = *(const float4*)&pe[((size_t)row * 256 + c_e) * 2];
                    const float ve = acc[mi][2 * p][r], vo = acc[mi][2 * p + 1][r];
                    *(unsigned*)&Qpos[(size_t)row * 256 + c_e] =
                        packbf(ve * cs.x - vo * cs.y, vo * cs.z + ve * cs.w);
                    float z = elu1(ve) * ks.x + elu1(vo) * ks.y;
                    z += __shfl_xor(z, 1); z += __shfl_xor(z, 2);
                    z += __shfl_xor(z, 4); z += __shfl_xor(z, 8);
                    if (low == 0) Zbuf[(size_t)row * 8 + head] = 1.f / (z + 1e-6f);
                }
            }
        }
    } else if constexpr (EPI == EPI_KV) {
        // K/V interleaved in tile-cols (bit5 of tc = V flag): K-half and V-half of
        // a wave read the SAME pe rows/channels -> pe HBM traffic halved.
        const int n = m0 >> 12;
#pragma unroll
        for (int p = 0; p < NI / 2; p++) {
            const int tcg = gnb + 32 * p;                  // group base (low<16 adds below bit4)
            const bool isK = ((tcg >> 5) & 1) == 0;
            const int c = ((tcg & ~63) >> 1) | (low << 1); // even channel in [0,256)
            const int nh = n * 8 + (c >> 5), d = c & 31;
            unsigned short* dst = isK ? KF : VF;
            float kel_e = 0.f, kel_o = 0.f;
#pragma unroll
            for (int mi = 0; mi < MI; mi++) {
                const int row0 = gmb + mi * 16 + quad * 4;
                const int s0 = row0 & 4095;
                unsigned short pk[8];
#pragma unroll
                for (int r = 0; r < 4; r++) {
                    const int row = row0 + r;
                    const float4 cs = *(const float4*)&pe[((size_t)row * 256 + c) * 2];
                    const float ve = acc[mi][2 * p][r], vo = acc[mi][2 * p + 1][r];
                    pk[r]     = f2bf(ve * cs.x - vo * cs.y);
                    pk[4 + r] = f2bf(vo * cs.z + ve * cs.w);
                    if (isK) { kel_e += elu1(ve); kel_o += elu1(vo); }
                }
                const size_t base = ((size_t)nh * 512 + (s0 >> 3)) * 32;
                *(uint2*)&dst[(base + d) * 8 + (s0 & 7)]     = *(const uint2*)&pk[0];
                *(uint2*)&dst[(base + d + 1) * 8 + (s0 & 7)] = *(const uint2*)&pk[4];
            }
            if (isK) {
                kel_e += __shfl_xor(kel_e, 16); kel_e += __shfl_xor(kel_e, 32);
                kel_o += __shfl_xor(kel_o, 16); kel_o += __shfl_xor(kel_o, 32);
                if (quad == 0) {
                    atomicAdd(&KsumA[n * 256 + c], kel_e);
                    atomicAdd(&KsumA[n * 256 + c + 1], kel_o);
                }
            }
        }
    } else {  // EPI_LN1 / EPI_LN2RES  (MT=64, NT=256, 2x2 waves: block owns full rows)
        __shared__ float2 lnp[2][64];
#pragma unroll
        for (int mi = 0; mi < MI; mi++)
#pragma unroll
            for (int r = 0; r < 4; r++) {
                float s1 = 0.f, s2 = 0.f;
#pragma unroll
                for (int ni = 0; ni < NI; ni++) {
                    const float v = acc[mi][ni][r];
                    s1 += v; s2 += v * v;
                }
                s1 += __shfl_xor(s1, 1); s2 += __shfl_xor(s2, 1);
                s1 += __shfl_xor(s1, 2); s2 += __shfl_xor(s2, 2);
                s1 += __shfl_xor(s1, 4); s2 += __shfl_xor(s2, 4);
                s1 += __shfl_xor(s1, 8); s2 += __shfl_xor(s2, 8);
                if (low == 0) lnp[wn][wm * WM + mi * 16 + quad * 4 + r] = make_float2(s1, s2);
            }
        __syncthreads();
#pragma unroll
        for (int mi = 0; mi < MI; mi++)
#pragma unroll
            for (int r = 0; r < 4; r++) {
                const int rl = wm * WM + mi * 16 + quad * 4 + r;
                const int row = m0 + rl;
                const float2 pa = lnp[0][rl], pb = lnp[1][rl];
                const float mean = (pa.x + pb.x) * (1.f / 256.f);
                const float var = (pa.y + pb.y) * (1.f / 256.f) - mean * mean;
                const float rstd = rsqrtf(var + 1e-5f);
#pragma unroll
                for (int p = 0; p < NI / 2; p++) {
                    const int c_e = chan_even(gnb, p, low);
                    const float2 gg = *(const float2*)&g[c_e];
                    const float2 bb = *(const float2*)&bta[c_e];
                    const float ve = acc[mi][2 * p][r], vo = acc[mi][2 * p + 1][r];
                    const float oe = (ve - mean) * rstd * gg.x + bb.x;
                    const float oo = (vo - mean) * rstd * gg.y + bb.y;
                    if constexpr (EPI == EPI_LN1) {
                        *(unsigned*)&A2out[(size_t)row * 512 + 256 + c_e] = packbf(oe, oo);
                    } else {
                        const float2 xv = *(const float2*)&xres[(size_t)row * 256 + c_e];
                        float2 o; o.x = xv.x + oe; o.y = xv.y + oo;
                        *(float2*)&outF[(size_t)row * 256 + c_e] = o;
                    }
                }
            }
    }
}

// ---------------- weight prep + workspace zeroing (replaces hipMemsetAsync) ----------------
// idx < 655360: weight transpose/permute/cast.  idx >= 655360: zero KVT+Ksum (67584 floats).
__global__ void prep_weights(const float* __restrict__ Wq, const float* __restrict__ Wk,
                             const float* __restrict__ Wv, const float* __restrict__ Wm,
                             const float* __restrict__ W1, const float* __restrict__ W2,
                             unsigned short* __restrict__ WqT, unsigned short* __restrict__ WkvT,
                             unsigned short* __restrict__ WmT, unsigned short* __restrict__ W1T,
                             unsigned short* __restrict__ W2T, float* __restrict__ zero_base) {
    const int idx = blockIdx.x * 256 + threadIdx.x;
    if (idx < 65536) {
        const int tc = idx >> 8, k = idx & 255;
        WqT[idx] = f2bf(Wq[(size_t)k * 256 + chan_of(tc)]);
    } else if (idx < 196608) {
        // K/V interleaved: tc bit5 = V flag; c = channel in [0,256)
        const int i = idx - 65536, tc = i >> 8, k = i & 255;
        const int f = (tc >> 5) & 1;
        const int c = ((tc & ~63) >> 1) | ((tc & 15) << 1) | ((tc >> 4) & 1);
        WkvT[i] = f2bf(f ? Wv[(size_t)k * 256 + c] : Wk[(size_t)k * 256 + c]);
    } else if (idx < 262144) {
        const int i = idx - 196608, tc = i >> 8, k = i & 255;
        WmT[i] = f2bf(Wm[(size_t)k * 256 + chan_of(tc)]);
    } else if (idx < 524288) {
        const int i = idx - 262144, tc = i >> 9, k = i & 511;
        W1T[i] = f2bf(W1[(size_t)k * 512 + chan_of(tc)]);
    } else if (idx < 655360) {
        const int i = idx - 524288, tc = i >> 9, k = i & 511;
        W2T[i] = f2bf(W2[(size_t)k * 256 + chan_of(tc)]);
    } else {
        zero_base[idx - 655360] = 0.f;   // KVT (65536) + Ksum (2048), contiguous
    }
}

// ---------------- fp32 [rows,256] -> bf16 with dst row-stride ----------------
__global__ void conv_bf16(const float* __restrict__ src, unsigned short* __restrict__ dst, int dstride) {
    const int idx = blockIdx.x * 256 + threadIdx.x;  // one per 4 elems
    const int row = idx >> 6;
    const int c0 = (idx & 63) * 4;
    const float4 v = *(const float4*)&src[(size_t)row * 256 + c0];
    unsigned short o[4] = {f2bf(v.x), f2bf(v.y), f2bf(v.z), f2bf(v.w)};
    *(uint2*)&dst[(size_t)row * dstride + c0] = *(const uint2*)o;
}

// ---------------- KV via MFMA from frag-major KF/VF: KVT[nh][v][d] ----------------
__global__ __launch_bounds__(256) void kv2_kernel(const unsigned short* __restrict__ KF,
                                                  const unsigned short* __restrict__ VF,
                                                  float* __restrict__ KVT) {
    const int nh = blockIdx.x, sc = blockIdx.y;
    const int t = threadIdx.x, lane = t & 63, w = t >> 6;
    const int quad = lane >> 4, low = lane & 15;
    const int sbase = sc * 1024 + w * 256;

    f32x4 acc[2][2];
#pragma unroll
    for (int i = 0; i < 2; i++)
#pragma unroll
        for (int j = 0; j < 2; j++) acc[i][j] = (f32x4){0.f, 0.f, 0.f, 0.f};

    for (int s0 = 0; s0 < 256; s0 += 32) {
        const int sk = sbase + s0 + quad * 8;
        const size_t cb = ((size_t)nh * 512 + (sk >> 3)) * 32;
        bf16x8 a[2], b[2];
#pragma unroll
        for (int mi = 0; mi < 2; mi++)
            a[mi] = *(const bf16x8*)&KF[(cb + mi * 16 + low) * 8];
#pragma unroll
        for (int ni = 0; ni < 2; ni++)
            b[ni] = *(const bf16x8*)&VF[(cb + ni * 16 + low) * 8];
#pragma unroll
        for (int mi = 0; mi < 2; mi++)
#pragma unroll
            for (int ni = 0; ni < 2; ni++)
                acc[mi][ni] = __builtin_amdgcn_mfma_f32_16x16x32_bf16(a[mi], b[ni], acc[mi][ni], 0, 0, 0);
    }

    __shared__ float red[4][1024];   // [wave][d*32+v]
#pragma unroll
    for (int mi = 0; mi < 2; mi++)
#pragma unroll
        for (int ni = 0; ni < 2; ni++)
#pragma unroll
            for (int r = 0; r < 4; r++)
                red[w][(mi * 16 + quad * 4 + r) * 32 + ni * 16 + low] = acc[mi][ni][r];
    __syncthreads();
#pragma unroll
    for (int k = 0; k < 4; k++) {
        const int i = t + k * 256;
        const float s = red[0][i] + red[1][i] + red[2][i] + red[3][i];
        atomicAdd(&KVT[(size_t)nh * 1024 + (size_t)(i & 31) * 32 + (i >> 5)], s);  // [v][d]
    }
}

// ---------------- queried = (Qpos @ KV[h]) * Z : M=32768, N=32, K=32 per head ----------------
__global__ __launch_bounds__(256) void attn_out_kernel(const unsigned short* __restrict__ Qpos,
                                                       const float* __restrict__ KVT,
                                                       const float* __restrict__ Zbuf,
                                                       unsigned short* __restrict__ Qrd) {
    const int h = blockIdx.y, mt = blockIdx.x;
    const int t = threadIdx.x, lane = t & 63, w = t >> 6;
    const int quad = lane >> 4, low = lane & 15;
    const int rbase = mt * 256 + w * 64;
    const int n = rbase >> 12;

    bf16x8 b[2];
#pragma unroll
    for (int ni = 0; ni < 2; ni++) {
        const float* src = &KVT[((size_t)(n * 8 + h) * 32 + ni * 16 + low) * 32 + quad * 8];
        short tmp[8];
#pragma unroll
        for (int j = 0; j < 8; j++) tmp[j] = (short)f2bf(src[j]);
        __builtin_memcpy(&b[ni], tmp, 16);
    }

    f32x4 acc[4][2];
#pragma unroll
    for (int i = 0; i < 4; i++)
#pragma unroll
        for (int j = 0; j < 2; j++) acc[i][j] = (f32x4){0.f, 0.f, 0.f, 0.f};

#pragma unroll
    for (int mi = 0; mi < 4; mi++) {
        const bf16x8 a = *(const bf16x8*)&Qpos[((size_t)(rbase + mi * 16 + low)) * 256 + h * 32 + quad * 8];
#pragma unroll
        for (int ni = 0; ni < 2; ni++)
            acc[mi][ni] = __builtin_amdgcn_mfma_f32_16x16x32_bf16(a, b[ni], acc[mi][ni], 0, 0, 0);
    }

#pragma unroll
    for (int mi = 0; mi < 4; mi++)
#pragma unroll
        for (int ni = 0; ni < 2; ni++)
#pragma unroll
            for (int r = 0; r < 4; r++) {
                const int row = rbase + mi * 16 + quad * 4 + r;
                const int col = h * 32 + ni * 16 + low;
                Qrd[(size_t)row * 256 + col] = f2bf(acc[mi][ni][r] * Zbuf[(size_t)row * 8 + h]);
            }
}

// ---------------- launch ----------------
extern "C" void kernel_launch(void* const* d_in, const int* in_sizes, int n_in,
                              void* d_out, int out_size, void* d_ws, size_t ws_size,
                              hipStream_t stream) {
    const float* x   = (const float*)d_in[0];
    const float* src = (const float*)d_in[1];
    const float* xpe = (const float*)d_in[2];
    const float* spe = (const float*)d_in[3];
    const float* Wq  = (const float*)d_in[4];
    const float* Wk  = (const float*)d_in[5];
    const float* Wv  = (const float*)d_in[6];
    const float* Wm  = (const float*)d_in[7];
    const float* W1  = (const float*)d_in[8];
    const float* W2  = (const float*)d_in[9];
    const float* g1  = (const float*)d_in[10];
    const float* b1  = (const float*)d_in[11];
    const float* g2  = (const float*)d_in[12];
    const float* b2  = (const float*)d_in[13];

    char* p = (char*)d_ws;
    unsigned short* WqT  = (unsigned short*)p; p += 256 * 256 * 2;
    unsigned short* WkvT = (unsigned short*)p; p += 512 * 256 * 2;
    unsigned short* WmT  = (unsigned short*)p; p += 256 * 256 * 2;
    unsigned short* W1T  = (unsigned short*)p; p += 512 * 512 * 2;
    unsigned short* W2T  = (unsigned short*)p; p += 256 * 512 * 2;
    float* KVT  = (float*)p; p += 64 * 1024 * 4;
    float* Ksum = (float*)p; p += 8 * 256 * 4;     // contiguous after KVT (zeroed together)
    float* Zbuf = (float*)p; p += (size_t)32768 * 8 * 4;
    unsigned short* A2   = (unsigned short*)p; p += (size_t)32768 * 512 * 2;  // cols 0-255: x, 256-511: LN1(msg)
    unsigned short* srcB = (unsigned short*)p; p += (size_t)32768 * 256 * 2;
    unsigned short* KF   = (unsigned short*)p; p += (size_t)32768 * 256 * 2;  // [nh][s/8][d][8]
    unsigned short* VF   = (unsigned short*)p; p += (size_t)32768 * 256 * 2;
    unsigned short* Qpos = (unsigned short*)p; p += (size_t)32768 * 256 * 2;
    unsigned short* Qrd  = (unsigned short*)p; p += (size_t)32768 * 256 * 2;
    unsigned short* hbuf = KF;   // 32MB over KF+VF (dead after kv2_kernel)

    // weights prep + KVT/Ksum zeroing: 655360 weight elems + 67584 zero floats = 2824 blocks
    prep_weights<<<2824, 256, 0, stream>>>(Wq, Wk, Wv, Wm, W1, W2,
                                           WqT, WkvT, WmT, W1T, W2T, KVT);
    conv_bf16<<<8192, 256, 0, stream>>>(x, A2, 512);
    conv_bf16<<<8192, 256, 0, stream>>>(src, srcB, 256);

    // K/V projection: rotary -> KF/VF frag layout, Ksum via atomics
    gemm_bt<64, 128, EPI_KV><<<dim3(512, 4), 256, 0, stream>>>(
        srcB, 256, WkvT, 256, nullptr, 0, spe, nullptr, Ksum,
        nullptr, nullptr, KF, VF, nullptr, nullptr, nullptr, nullptr, nullptr);
    kv2_kernel<<<dim3(64, 4), 256, 0, stream>>>(KF, VF, KVT);

    // Q projection: rotary + fused Z (Ksum ready)
    gemm_bt<64, 128, EPI_Q><<<dim3(512, 2), 256, 0, stream>>>(
        A2, 512, WqT, 256, nullptr, 0, xpe, Ksum, nullptr,
        Zbuf, Qpos, nullptr, nullptr, nullptr, nullptr, nullptr, nullptr, nullptr);

    attn_out_kernel<<<dim3(128, 8), 256, 0, stream>>>(Qpos, KVT, Zbuf, Qrd);

    // message = queried @ Wm -> LN1 -> A2 cols 256-511
    gemm_bt<64, 256, EPI_LN1><<<512, 256, 0, stream>>>(
        Qrd, 256, WmT, 256, nullptr, 0, nullptr, nullptr, nullptr,
        nullptr, nullptr, nullptr, nullptr, g1, b1, A2, nullptr, nullptr);

    // h = relu([x, message] @ W1)
    gemm_bt<64, 128, EPI_RELU><<<dim3(512, 4), 256, 0, stream>>>(
        A2, 512, W1T, 512, hbuf, 512, nullptr, nullptr, nullptr,
        nullptr, nullptr, nullptr, nullptr, nullptr, nullptr, nullptr, nullptr, nullptr);

    // out = x + LN2(h @ W2)
    gemm_bt<64, 256, EPI_LN2RES><<<512, 256, 0, stream>>>(
        hbuf, 512, W2T, 512, nullptr, 0, nullptr, nullptr, nullptr,
        nullptr, nullptr, nullptr, nullptr, g2, b2, nullptr, x, (float*)d_out);
}

// Round 6
// 378.089 us; speedup vs baseline: 1.0964x; 1.0964x over previous
//
#include <hip/hip_runtime.h>

// ---------------- helpers ----------------
typedef __attribute__((ext_vector_type(8))) short bf16x8;   // 8 bf16 = 4 VGPRs
typedef __attribute__((ext_vector_type(4))) float f32x4;

__device__ __forceinline__ float bf2f(unsigned short b) {
    unsigned u = ((unsigned)b) << 16; float f;
    __builtin_memcpy(&f, &u, 4); return f;
}
__device__ __forceinline__ unsigned short f2bf(float f) {
    unsigned u; __builtin_memcpy(&u, &f, 4);
    unsigned r = u + 0x7FFFu + ((u >> 16) & 1u);   // RNE
    return (unsigned short)(r >> 16);
}
__device__ __forceinline__ unsigned packbf(float a, float b) {
    return (unsigned)f2bf(a) | ((unsigned)f2bf(b) << 16);
}
__device__ __forceinline__ float elu1(float v) { return v > 0.f ? v + 1.f : __expf(v); }

__device__ __forceinline__ void async_copy16(const unsigned short* g, unsigned short* l) {
    __builtin_amdgcn_global_load_lds(
        (const __attribute__((address_space(1))) unsigned int*)g,
        (__attribute__((address_space(3))) unsigned int*)l, 16, 0, 0);
}

// tile-col -> channel permutation: lane low holds channels (2*low, 2*low+1) in adjacent ni
__device__ __host__ __forceinline__ int chan_of(int tc) {
    return (tc & ~63) | ((tc & 15) << 1) | ((tc >> 4) & 1) | (((tc >> 5) & 1) << 5);
}
__device__ __forceinline__ int chan_even(int gnb, int p, int low) {
    const int tc = gnb + 32 * p + low;   // ni = 2p  (bit4 = 0)
    return (tc & ~63) | ((tc & 15) << 1) | (((tc >> 5) & 1) << 5);
}

#define EPI_Q 1        // Wq: rotary + Z (needs Ksum), permuted
#define EPI_KV 2       // Wk|Wv interleaved: rotary + KF/VF frag store + Ksum atomics
#define EPI_LN1 3      // Wm: LN1 -> A2 cols 256-511, permuted

// ---------------- bf16 GEMM: C[M,N] = A[M,K](lda) @ B^T[N,K] ----------------
// Round-4 structure (proven best): ring + counted vmcnt, PF=2 depth-3.
template <int MT, int NT, int EPI>
__global__ __launch_bounds__(256) void gemm_bt(
    const unsigned short* __restrict__ A, int lda,
    const unsigned short* __restrict__ B, int K,
    const float* __restrict__ pe,
    const float* __restrict__ KsumC, float* __restrict__ KsumA,
    float* __restrict__ Zbuf, unsigned short* __restrict__ Qpos,
    unsigned short* __restrict__ KF, unsigned short* __restrict__ VF,
    const float* __restrict__ g, const float* __restrict__ bta,
    unsigned short* __restrict__ A2out)
{
    constexpr int WM = MT / 2, WN = NT / 2, MI = WM / 16, NI = WN / 16;
    constexpr int LPS = 1 + NT / 64;          // loads per stage per thread (vmcnt units)
    constexpr int PF = 2;                     // stages in flight
    constexpr int RD = PF + 1;                // ring depth
    static_assert(MT == 64, "A staging assumes MT*4 == 256 chunks");
    __shared__ unsigned short Asm[RD][MT * 32];
    __shared__ unsigned short Bsm[RD][NT * 32];
    const int t = threadIdx.x;
    const int lane = t & 63, w = t >> 6;
    const int wm = w & 1, wn = w >> 1;
    const int quad = lane >> 4, low = lane & 15;
    const int m0 = blockIdx.x * MT, n0 = blockIdx.y * NT;

    f32x4 acc[MI][NI];
#pragma unroll
    for (int i = 0; i < MI; i++)
#pragma unroll
        for (int j = 0; j < NI; j++) acc[i][j] = (f32x4){0.f, 0.f, 0.f, 0.f};

    // stage one 32-K tile into ring buffer `buf`.
    // source part index is XOR-swizzled so the linear global_load_lds write
    // produces a swizzled LDS layout (swizzle source + read, dest linear).
    auto stage = [&](int k0, int buf) {
        {   // A: 256 chunks, 1 per thread
            const int row = t >> 2;
            const int part = (t & 3) ^ ((t >> 3) & 3);
            async_copy16(A + (size_t)(m0 + row) * lda + k0 + part * 8,
                         &Asm[buf][(w * 64) * 8]);
        }
#pragma unroll
        for (int i = 0; i < NT / 64; i++) {
            const int chunk = i * 256 + t;
            const int row = chunk >> 2;
            const int part = (chunk & 3) ^ ((chunk >> 3) & 3);
            async_copy16(B + (size_t)(n0 + row) * K + k0 + part * 8,
                         &Bsm[buf][(i * 256 + w * 64) * 8]);
        }
    };

    const int nk = K >> 5;                   // >= 8 always
    const int swz = (low >> 1) & 3;          // read-side swizzle key (= (row>>1)&3)
#pragma unroll
    for (int i = 0; i < PF; i++) stage(i << 5, i);
    int kb = 0, sb = PF;                     // read buffer, stage buffer
    for (int ks = 0; ks < nk; ks++) {
        const int rem = nk - 1 - ks;         // stages allowed to stay in flight
        __builtin_amdgcn_sched_barrier(0);
        if constexpr (LPS == 3) {
            if (rem >= 1)      asm volatile("s_waitcnt vmcnt(3)" ::: "memory");
            else               asm volatile("s_waitcnt vmcnt(0)" ::: "memory");
        } else {                             // LPS == 5
            if (rem >= 1)      asm volatile("s_waitcnt vmcnt(5)" ::: "memory");
            else               asm volatile("s_waitcnt vmcnt(0)" ::: "memory");
        }
        __builtin_amdgcn_s_barrier();        // all waves' tile-ks loads landed
        __builtin_amdgcn_sched_barrier(0);
        if (ks + PF < nk) stage((ks + PF) << 5, sb);   // refill freed buffer
        bf16x8 a[MI], b[NI];
#pragma unroll
        for (int mi = 0; mi < MI; mi++)
            a[mi] = *(const bf16x8*)&Asm[kb][(wm * WM + mi * 16 + low) * 32 + ((quad ^ swz)) * 8];
#pragma unroll
        for (int ni = 0; ni < NI; ni++)
            b[ni] = *(const bf16x8*)&Bsm[kb][(wn * WN + ni * 16 + low) * 32 + ((quad ^ swz)) * 8];
#pragma unroll
        for (int mi = 0; mi < MI; mi++)
#pragma unroll
            for (int ni = 0; ni < NI; ni++)
                acc[mi][ni] = __builtin_amdgcn_mfma_f32_16x16x32_bf16(a[mi], b[ni], acc[mi][ni], 0, 0, 0);
        kb = (kb + 1 == RD) ? 0 : kb + 1;
        sb = (sb + 1 == RD) ? 0 : sb + 1;
    }

    const int gmb = m0 + wm * WM, gnb = n0 + wn * WN;

    if constexpr (EPI == EPI_Q) {
        const int n = m0 >> 12;
#pragma unroll
        for (int p = 0; p < NI / 2; p++) {
            const int c_e = chan_even(gnb, p, low);
            const int head = c_e >> 5;
            const float2 ks = *(const float2*)&KsumC[n * 256 + c_e];
#pragma unroll
            for (int mi = 0; mi < MI; mi++) {
#pragma unroll
                for (int r = 0; r < 4; r++) {
                    const int row = gmb + mi * 16 + quad * 4 + r;
                    const float4 cs = *(const float4*)&pe[((size_t)row * 256 + c_e) * 2];
                    const float ve = acc[mi][2 * p][r], vo = acc[mi][2 * p + 1][r];
                    *(unsigned*)&Qpos[(size_t)row * 256 + c_e] =
                        packbf(ve * cs.x - vo * cs.y, vo * cs.z + ve * cs.w);
                    float z = elu1(ve) * ks.x + elu1(vo) * ks.y;
                    z += __shfl_xor(z, 1); z += __shfl_xor(z, 2);
                    z += __shfl_xor(z, 4); z += __shfl_xor(z, 8);
                    if (low == 0) Zbuf[(size_t)row * 8 + head] = 1.f / (z + 1e-6f);
                }
            }
        }
    } else if constexpr (EPI == EPI_KV) {
        // K/V interleaved in tile-cols (bit5 of tc = V flag): K-half and V-half of
        // a wave read the SAME pe rows/channels -> pe HBM traffic halved.
        const int n = m0 >> 12;
#pragma unroll
        for (int p = 0; p < NI / 2; p++) {
            const int tcg = gnb + 32 * p;                  // group base (low<16 adds below bit4)
            const bool isK = ((tcg >> 5) & 1) == 0;
            const int c = ((tcg & ~63) >> 1) | (low << 1); // even channel in [0,256)
            const int nh = n * 8 + (c >> 5), d = c & 31;
            unsigned short* dst = isK ? KF : VF;
            float kel_e = 0.f, kel_o = 0.f;
#pragma unroll
            for (int mi = 0; mi < MI; mi++) {
                const int row0 = gmb + mi * 16 + quad * 4;
                const int s0 = row0 & 4095;
                unsigned short pk[8];
#pragma unroll
                for (int r = 0; r < 4; r++) {
                    const int row = row0 + r;
                    const float4 cs = *(const float4*)&pe[((size_t)row * 256 + c) * 2];
                    const float ve = acc[mi][2 * p][r], vo = acc[mi][2 * p + 1][r];
                    pk[r]     = f2bf(ve * cs.x - vo * cs.y);
                    pk[4 + r] = f2bf(vo * cs.z + ve * cs.w);
                    if (isK) { kel_e += elu1(ve); kel_o += elu1(vo); }
                }
                const size_t base = ((size_t)nh * 512 + (s0 >> 3)) * 32;
                *(uint2*)&dst[(base + d) * 8 + (s0 & 7)]     = *(const uint2*)&pk[0];
                *(uint2*)&dst[(base + d + 1) * 8 + (s0 & 7)] = *(const uint2*)&pk[4];
            }
            if (isK) {
                kel_e += __shfl_xor(kel_e, 16); kel_e += __shfl_xor(kel_e, 32);
                kel_o += __shfl_xor(kel_o, 16); kel_o += __shfl_xor(kel_o, 32);
                if (quad == 0) {
                    atomicAdd(&KsumA[n * 256 + c], kel_e);
                    atomicAdd(&KsumA[n * 256 + c + 1], kel_o);
                }
            }
        }
    } else {  // EPI_LN1  (MT=64, NT=256, 2x2 waves: block owns full rows)
        __shared__ float2 lnp[2][64];
#pragma unroll
        for (int mi = 0; mi < MI; mi++)
#pragma unroll
            for (int r = 0; r < 4; r++) {
                float s1 = 0.f, s2 = 0.f;
#pragma unroll
                for (int ni = 0; ni < NI; ni++) {
                    const float v = acc[mi][ni][r];
                    s1 += v; s2 += v * v;
                }
                s1 += __shfl_xor(s1, 1); s2 += __shfl_xor(s2, 1);
                s1 += __shfl_xor(s1, 2); s2 += __shfl_xor(s2, 2);
                s1 += __shfl_xor(s1, 4); s2 += __shfl_xor(s2, 4);
                s1 += __shfl_xor(s1, 8); s2 += __shfl_xor(s2, 8);
                if (low == 0) lnp[wn][wm * WM + mi * 16 + quad * 4 + r] = make_float2(s1, s2);
            }
        __syncthreads();
#pragma unroll
        for (int mi = 0; mi < MI; mi++)
#pragma unroll
            for (int r = 0; r < 4; r++) {
                const int rl = wm * WM + mi * 16 + quad * 4 + r;
                const int row = m0 + rl;
                const float2 pa = lnp[0][rl], pb = lnp[1][rl];
                const float mean = (pa.x + pb.x) * (1.f / 256.f);
                const float var = (pa.y + pb.y) * (1.f / 256.f) - mean * mean;
                const float rstd = rsqrtf(var + 1e-5f);
#pragma unroll
                for (int p = 0; p < NI / 2; p++) {
                    const int c_e = chan_even(gnb, p, low);
                    const float2 gg = *(const float2*)&g[c_e];
                    const float2 bb = *(const float2*)&bta[c_e];
                    const float ve = acc[mi][2 * p][r], vo = acc[mi][2 * p + 1][r];
                    const float oe = (ve - mean) * rstd * gg.x + bb.x;
                    const float oo = (vo - mean) * rstd * gg.y + bb.y;
                    *(unsigned*)&A2out[(size_t)row * 512 + 256 + c_e] = packbf(oe, oo);
                }
            }
    }
}

// ---------------- fused FFN: out = x + LN2( relu([x,msg]@W1^T) @ W2^T ) ------
// One block = 64 rows. Phase 1: h = relu(A2[64x512] @ W1T^T) kept in LDS (64KB,
// XOR-swizzled). Phase 2: msg2 = h @ W2T^T from LDS; LN2 + residual -> fp32 out.
// Deletes the hbuf HBM round-trip (64 MB) and one dispatch.
__global__ __launch_bounds__(512) void ffn_kernel(
    const unsigned short* __restrict__ A2,   // [32768][512] bf16 (x || msg)
    const unsigned short* __restrict__ W1T,  // [512 tc][512 k] bf16 (permuted tc)
    const unsigned short* __restrict__ W2T,  // [256 tc][512 k] bf16 (permuted tc)
    const float* __restrict__ g, const float* __restrict__ bta,
    const float* __restrict__ xres, float* __restrict__ outF)
{
    __shared__ unsigned short Hs[64 * 512];        // 64 KB
    __shared__ unsigned short Bst[2][512 * 32];    // 64 KB (phase2 uses first 16KB)
    __shared__ unsigned short Ast[2][64 * 32];     // 8 KB
    __shared__ float2 lnp[4][64];
    const int t = threadIdx.x;
    const int lane = t & 63, w = t >> 6;           // 8 waves
    const int wm = w & 1, wn = w >> 1;             // 2 (M) x 4 (N)
    const int quad = lane >> 4, low = lane & 15;
    const int m0 = blockIdx.x * 64;
    const int swz = (low >> 1) & 3;

    // ---------------- phase 1: C1[64x512] = A2 @ W1T^T (WN=128, NI=8) -------
    f32x4 acc[2][8];
#pragma unroll
    for (int i = 0; i < 2; i++)
#pragma unroll
        for (int j = 0; j < 8; j++) acc[i][j] = (f32x4){0.f, 0.f, 0.f, 0.f};

    auto stage1 = [&](int k0, int buf) {
        if (w < 4) {   // A: 256 chunks (wave-uniform guard)
            const int row = t >> 2;
            const int part = (t & 3) ^ ((t >> 3) & 3);
            async_copy16(A2 + (size_t)(m0 + row) * 512 + k0 + part * 8,
                         &Ast[buf][(w * 64) * 8]);
        }
#pragma unroll
        for (int i = 0; i < 4; i++) {   // B: 512 rows x 4 parts = 2048 chunks
            const int chunk = i * 512 + t;
            const int row = chunk >> 2;
            const int part = (chunk & 3) ^ ((chunk >> 3) & 3);
            async_copy16(W1T + (size_t)row * 512 + k0 + part * 8,
                         &Bst[buf][(i * 512 + w * 64) * 8]);
        }
    };

    stage1(0, 0);
    for (int ks = 0; ks < 16; ks++) {
        const int kb = ks & 1;
        __builtin_amdgcn_sched_barrier(0);
        asm volatile("s_waitcnt vmcnt(0)" ::: "memory");
        __builtin_amdgcn_s_barrier();
        __builtin_amdgcn_sched_barrier(0);
        if (ks + 1 < 16) stage1((ks + 1) << 5, kb ^ 1);
        bf16x8 a[2], b[8];
#pragma unroll
        for (int mi = 0; mi < 2; mi++)
            a[mi] = *(const bf16x8*)&Ast[kb][(wm * 32 + mi * 16 + low) * 32 + (quad ^ swz) * 8];
#pragma unroll
        for (int ni = 0; ni < 8; ni++)
            b[ni] = *(const bf16x8*)&Bst[kb][(wn * 128 + ni * 16 + low) * 32 + (quad ^ swz) * 8];
#pragma unroll
        for (int mi = 0; mi < 2; mi++)
#pragma unroll
            for (int ni = 0; ni < 8; ni++)
                acc[mi][ni] = __builtin_amdgcn_mfma_f32_16x16x32_bf16(a[mi], b[ni], acc[mi][ni], 0, 0, 0);
    }

    // relu -> Hs in NATURAL channel order, byte-XOR swizzle per row
    const int gnb1 = wn * 128;
#pragma unroll
    for (int mi = 0; mi < 2; mi++)
#pragma unroll
        for (int p = 0; p < 4; p++) {
            const int c_e = chan_even(gnb1, p, low);       // even channel 0..510
#pragma unroll
            for (int r = 0; r < 4; r++) {
                const int row = wm * 32 + mi * 16 + quad * 4 + r;   // 0..63 local
                const float ve = acc[mi][2 * p][r], vo = acc[mi][2 * p + 1][r];
                const int col = c_e ^ ((row & 7) << 3);    // swizzle elem bits 3..5
                *(unsigned*)&Hs[row * 512 + col] =
                    packbf(ve > 0.f ? ve : 0.f, vo > 0.f ? vo : 0.f);
            }
        }
    __syncthreads();   // h complete & visible; phase-1 LDS reads all done

    // ---------------- phase 2: msg2[64x256] = h @ W2T^T (WN2=64, NI2=4) -----
    f32x4 acc2[2][4];
#pragma unroll
    for (int i = 0; i < 2; i++)
#pragma unroll
        for (int j = 0; j < 4; j++) acc2[i][j] = (f32x4){0.f, 0.f, 0.f, 0.f};

    auto stage2 = [&](int k0, int buf) {
#pragma unroll
        for (int i = 0; i < 2; i++) {   // 256 rows x 4 parts = 1024 chunks
            const int chunk = i * 512 + t;
            const int row = chunk >> 2;
            const int part = (chunk & 3) ^ ((chunk >> 3) & 3);
            async_copy16(W2T + (size_t)row * 512 + k0 + part * 8,
                         &Bst[buf][(i * 512 + w * 64) * 8]);
        }
    };

    stage2(0, 0);
    for (int ks = 0; ks < 16; ks++) {
        const int kb = ks & 1;
        __builtin_amdgcn_sched_barrier(0);
        asm volatile("s_waitcnt vmcnt(0)" ::: "memory");
        __builtin_amdgcn_s_barrier();
        __builtin_amdgcn_sched_barrier(0);
        if (ks + 1 < 16) stage2((ks + 1) << 5, kb ^ 1);
        bf16x8 a[2], b[4];
#pragma unroll
        for (int mi = 0; mi < 2; mi++) {
            const int row = wm * 32 + mi * 16 + low;
            a[mi] = *(const bf16x8*)&Hs[row * 512 + ((ks * 32 + quad * 8) ^ ((row & 7) << 3))];
        }
#pragma unroll
        for (int ni = 0; ni < 4; ni++)
            b[ni] = *(const bf16x8*)&Bst[kb][(wn * 64 + ni * 16 + low) * 32 + (quad ^ swz) * 8];
#pragma unroll
        for (int mi = 0; mi < 2; mi++)
#pragma unroll
            for (int ni = 0; ni < 4; ni++)
                acc2[mi][ni] = __builtin_amdgcn_mfma_f32_16x16x32_bf16(a[mi], b[ni], acc2[mi][ni], 0, 0, 0);
    }

    // ---------------- LN2 + residual -> fp32 out ----------------------------
#pragma unroll
    for (int mi = 0; mi < 2; mi++)
#pragma unroll
        for (int r = 0; r < 4; r++) {
            float s1 = 0.f, s2 = 0.f;
#pragma unroll
            for (int ni = 0; ni < 4; ni++) {
                const float v = acc2[mi][ni][r];
                s1 += v; s2 += v * v;
            }
            s1 += __shfl_xor(s1, 1); s2 += __shfl_xor(s2, 1);
            s1 += __shfl_xor(s1, 2); s2 += __shfl_xor(s2, 2);
            s1 += __shfl_xor(s1, 4); s2 += __shfl_xor(s2, 4);
            s1 += __shfl_xor(s1, 8); s2 += __shfl_xor(s2, 8);
            if (low == 0) lnp[wn][wm * 32 + mi * 16 + quad * 4 + r] = make_float2(s1, s2);
        }
    __syncthreads();
#pragma unroll
    for (int mi = 0; mi < 2; mi++)
#pragma unroll
        for (int r = 0; r < 4; r++) {
            const int rl = wm * 32 + mi * 16 + quad * 4 + r;
            const int row = m0 + rl;
            const float2 p0 = lnp[0][rl], p1 = lnp[1][rl];
            const float2 p2 = lnp[2][rl], p3 = lnp[3][rl];
            const float mean = (p0.x + p1.x + p2.x + p3.x) * (1.f / 256.f);
            const float var = (p0.y + p1.y + p2.y + p3.y) * (1.f / 256.f) - mean * mean;
            const float rstd = rsqrtf(var + 1e-5f);
#pragma unroll
            for (int p = 0; p < 2; p++) {
                const int c_e = chan_even(wn * 64, p, low);
                const float2 gg = *(const float2*)&g[c_e];
                const float2 bb = *(const float2*)&bta[c_e];
                const float ve = acc2[mi][2 * p][r], vo = acc2[mi][2 * p + 1][r];
                const float oe = (ve - mean) * rstd * gg.x + bb.x;
                const float oo = (vo - mean) * rstd * gg.y + bb.y;
                const float2 xv = *(const float2*)&xres[(size_t)row * 256 + c_e];
                float2 o; o.x = xv.x + oe; o.y = xv.y + oo;
                *(float2*)&outF[(size_t)row * 256 + c_e] = o;
            }
        }
}

// ---------------- weight prep + workspace zeroing (replaces hipMemsetAsync) ----------------
// idx < 655360: weight transpose/permute/cast.  idx >= 655360: zero KVT+Ksum (67584 floats).
__global__ void prep_weights(const float* __restrict__ Wq, const float* __restrict__ Wk,
                             const float* __restrict__ Wv, const float* __restrict__ Wm,
                             const float* __restrict__ W1, const float* __restrict__ W2,
                             unsigned short* __restrict__ WqT, unsigned short* __restrict__ WkvT,
                             unsigned short* __restrict__ WmT, unsigned short* __restrict__ W1T,
                             unsigned short* __restrict__ W2T, float* __restrict__ zero_base) {
    const int idx = blockIdx.x * 256 + threadIdx.x;
    if (idx < 65536) {
        const int tc = idx >> 8, k = idx & 255;
        WqT[idx] = f2bf(Wq[(size_t)k * 256 + chan_of(tc)]);
    } else if (idx < 196608) {
        // K/V interleaved: tc bit5 = V flag; c = channel in [0,256)
        const int i = idx - 65536, tc = i >> 8, k = i & 255;
        const int f = (tc >> 5) & 1;
        const int c = ((tc & ~63) >> 1) | ((tc & 15) << 1) | ((tc >> 4) & 1);
        WkvT[i] = f2bf(f ? Wv[(size_t)k * 256 + c] : Wk[(size_t)k * 256 + c]);
    } else if (idx < 262144) {
        const int i = idx - 196608, tc = i >> 8, k = i & 255;
        WmT[i] = f2bf(Wm[(size_t)k * 256 + chan_of(tc)]);
    } else if (idx < 524288) {
        const int i = idx - 262144, tc = i >> 9, k = i & 511;
        W1T[i] = f2bf(W1[(size_t)k * 512 + chan_of(tc)]);
    } else if (idx < 655360) {
        const int i = idx - 524288, tc = i >> 9, k = i & 511;
        W2T[i] = f2bf(W2[(size_t)k * 256 + chan_of(tc)]);
    } else {
        zero_base[idx - 655360] = 0.f;   // KVT (65536) + Ksum (2048), contiguous
    }
}

// ---------------- fp32 [rows,256] -> bf16 with dst row-stride ----------------
__global__ void conv_bf16(const float* __restrict__ src, unsigned short* __restrict__ dst, int dstride) {
    const int idx = blockIdx.x * 256 + threadIdx.x;  // one per 4 elems
    const int row = idx >> 6;
    const int c0 = (idx & 63) * 4;
    const float4 v = *(const float4*)&src[(size_t)row * 256 + c0];
    unsigned short o[4] = {f2bf(v.x), f2bf(v.y), f2bf(v.z), f2bf(v.w)};
    *(uint2*)&dst[(size_t)row * dstride + c0] = *(const uint2*)o;
}

// ---------------- KV via MFMA from frag-major KF/VF: KVT[nh][v][d] ----------------
__global__ __launch_bounds__(256) void kv2_kernel(const unsigned short* __restrict__ KF,
                                                  const unsigned short* __restrict__ VF,
                                                  float* __restrict__ KVT) {
    const int nh = blockIdx.x, sc = blockIdx.y;
    const int t = threadIdx.x, lane = t & 63, w = t >> 6;
    const int quad = lane >> 4, low = lane & 15;
    const int sbase = sc * 1024 + w * 256;

    f32x4 acc[2][2];
#pragma unroll
    for (int i = 0; i < 2; i++)
#pragma unroll
        for (int j = 0; j < 2; j++) acc[i][j] = (f32x4){0.f, 0.f, 0.f, 0.f};

    for (int s0 = 0; s0 < 256; s0 += 32) {
        const int sk = sbase + s0 + quad * 8;
        const size_t cb = ((size_t)nh * 512 + (sk >> 3)) * 32;
        bf16x8 a[2], b[2];
#pragma unroll
        for (int mi = 0; mi < 2; mi++)
            a[mi] = *(const bf16x8*)&KF[(cb + mi * 16 + low) * 8];
#pragma unroll
        for (int ni = 0; ni < 2; ni++)
            b[ni] = *(const bf16x8*)&VF[(cb + ni * 16 + low) * 8];
#pragma unroll
        for (int mi = 0; mi < 2; mi++)
#pragma unroll
            for (int ni = 0; ni < 2; ni++)
                acc[mi][ni] = __builtin_amdgcn_mfma_f32_16x16x32_bf16(a[mi], b[ni], acc[mi][ni], 0, 0, 0);
    }

    __shared__ float red[4][1024];   // [wave][d*32+v]
#pragma unroll
    for (int mi = 0; mi < 2; mi++)
#pragma unroll
        for (int ni = 0; ni < 2; ni++)
#pragma unroll
            for (int r = 0; r < 4; r++)
                red[w][(mi * 16 + quad * 4 + r) * 32 + ni * 16 + low] = acc[mi][ni][r];
    __syncthreads();
#pragma unroll
    for (int k = 0; k < 4; k++) {
        const int i = t + k * 256;
        const float s = red[0][i] + red[1][i] + red[2][i] + red[3][i];
        atomicAdd(&KVT[(size_t)nh * 1024 + (size_t)(i & 31) * 32 + (i >> 5)], s);  // [v][d]
    }
}

// ---------------- queried = (Qpos @ KV[h]) * Z : M=32768, N=32, K=32 per head ----------------
__global__ __launch_bounds__(256) void attn_out_kernel(const unsigned short* __restrict__ Qpos,
                                                       const float* __restrict__ KVT,
                                                       const float* __restrict__ Zbuf,
                                                       unsigned short* __restrict__ Qrd) {
    const int h = blockIdx.y, mt = blockIdx.x;
    const int t = threadIdx.x, lane = t & 63, w = t >> 6;
    const int quad = lane >> 4, low = lane & 15;
    const int rbase = mt * 256 + w * 64;
    const int n = rbase >> 12;

    bf16x8 b[2];
#pragma unroll
    for (int ni = 0; ni < 2; ni++) {
        const float* src = &KVT[((size_t)(n * 8 + h) * 32 + ni * 16 + low) * 32 + quad * 8];
        short tmp[8];
#pragma unroll
        for (int j = 0; j < 8; j++) tmp[j] = (short)f2bf(src[j]);
        __builtin_memcpy(&b[ni], tmp, 16);
    }

    f32x4 acc[4][2];
#pragma unroll
    for (int i = 0; i < 4; i++)
#pragma unroll
        for (int j = 0; j < 2; j++) acc[i][j] = (f32x4){0.f, 0.f, 0.f, 0.f};

#pragma unroll
    for (int mi = 0; mi < 4; mi++) {
        const bf16x8 a = *(const bf16x8*)&Qpos[((size_t)(rbase + mi * 16 + low)) * 256 + h * 32 + quad * 8];
#pragma unroll
        for (int ni = 0; ni < 2; ni++)
            acc[mi][ni] = __builtin_amdgcn_mfma_f32_16x16x32_bf16(a, b[ni], acc[mi][ni], 0, 0, 0);
    }

#pragma unroll
    for (int mi = 0; mi < 4; mi++)
#pragma unroll
        for (int ni = 0; ni < 2; ni++)
#pragma unroll
            for (int r = 0; r < 4; r++) {
                const int row = rbase + mi * 16 + quad * 4 + r;
                const int col = h * 32 + ni * 16 + low;
                Qrd[(size_t)row * 256 + col] = f2bf(acc[mi][ni][r] * Zbuf[(size_t)row * 8 + h]);
            }
}

// ---------------- launch ----------------
extern "C" void kernel_launch(void* const* d_in, const int* in_sizes, int n_in,
                              void* d_out, int out_size, void* d_ws, size_t ws_size,
                              hipStream_t stream) {
    const float* x   = (const float*)d_in[0];
    const float* src = (const float*)d_in[1];
    const float* xpe = (const float*)d_in[2];
    const float* spe = (const float*)d_in[3];
    const float* Wq  = (const float*)d_in[4];
    const float* Wk  = (const float*)d_in[5];
    const float* Wv  = (const float*)d_in[6];
    const float* Wm  = (const float*)d_in[7];
    const float* W1  = (const float*)d_in[8];
    const float* W2  = (const float*)d_in[9];
    const float* g1  = (const float*)d_in[10];
    const float* b1  = (const float*)d_in[11];
    const float* g2  = (const float*)d_in[12];
    const float* b2  = (const float*)d_in[13];

    char* p = (char*)d_ws;
    unsigned short* WqT  = (unsigned short*)p; p += 256 * 256 * 2;
    unsigned short* WkvT = (unsigned short*)p; p += 512 * 256 * 2;
    unsigned short* WmT  = (unsigned short*)p; p += 256 * 256 * 2;
    unsigned short* W1T  = (unsigned short*)p; p += 512 * 512 * 2;
    unsigned short* W2T  = (unsigned short*)p; p += 256 * 512 * 2;
    float* KVT  = (float*)p; p += 64 * 1024 * 4;
    float* Ksum = (float*)p; p += 8 * 256 * 4;     // contiguous after KVT (zeroed together)
    float* Zbuf = (float*)p; p += (size_t)32768 * 8 * 4;
    unsigned short* A2   = (unsigned short*)p; p += (size_t)32768 * 512 * 2;  // cols 0-255: x, 256-511: LN1(msg)
    unsigned short* srcB = (unsigned short*)p; p += (size_t)32768 * 256 * 2;
    unsigned short* KF   = (unsigned short*)p; p += (size_t)32768 * 256 * 2;  // [nh][s/8][d][8]
    unsigned short* VF   = (unsigned short*)p; p += (size_t)32768 * 256 * 2;
    unsigned short* Qpos = (unsigned short*)p; p += (size_t)32768 * 256 * 2;
    unsigned short* Qrd  = (unsigned short*)p; p += (size_t)32768 * 256 * 2;

    // weights prep + KVT/Ksum zeroing: 655360 weight elems + 67584 zero floats = 2824 blocks
    prep_weights<<<2824, 256, 0, stream>>>(Wq, Wk, Wv, Wm, W1, W2,
                                           WqT, WkvT, WmT, W1T, W2T, KVT);
    conv_bf16<<<8192, 256, 0, stream>>>(x, A2, 512);
    conv_bf16<<<8192, 256, 0, stream>>>(src, srcB, 256);

    // K/V projection: rotary -> KF/VF frag layout, Ksum via atomics
    gemm_bt<64, 128, EPI_KV><<<dim3(512, 4), 256, 0, stream>>>(
        srcB, 256, WkvT, 256, spe, nullptr, Ksum,
        nullptr, nullptr, KF, VF, nullptr, nullptr, nullptr);
    kv2_kernel<<<dim3(64, 4), 256, 0, stream>>>(KF, VF, KVT);

    // Q projection: rotary + fused Z (Ksum ready)
    gemm_bt<64, 128, EPI_Q><<<dim3(512, 2), 256, 0, stream>>>(
        A2, 512, WqT, 256, xpe, Ksum, nullptr,
        Zbuf, Qpos, nullptr, nullptr, nullptr, nullptr, nullptr);

    attn_out_kernel<<<dim3(128, 8), 256, 0, stream>>>(Qpos, KVT, Zbuf, Qrd);

    // message = queried @ Wm -> LN1 -> A2 cols 256-511
    gemm_bt<64, 256, EPI_LN1><<<512, 256, 0, stream>>>(
        Qrd, 256, WmT, 256, nullptr, nullptr, nullptr,
        nullptr, nullptr, nullptr, nullptr, g1, b1, A2);

    // out = x + LN2( relu([x,msg]@W1^T) @ W2^T )  -- fused, h stays in LDS
    ffn_kernel<<<512, 512, 0, stream>>>(A2, W1T, W2T, g2, b2, x, (float*)d_out);
}